// Round 10
// baseline (395.365 us; speedup 1.0000x reference)
//
#include <hip/hip_runtime.h>
#include <hip/hip_bf16.h>

// GCN link-prediction: 2x GCNConv(128->128) + edge dot scoring.
// Round 10: (1) fuse agg1+gemm2 — per-wave 32-node aggregate into private LDS
// tile (XOR-swizzled, barrier-free) then MFMA with W2 (kills X1 round trip);
// (2) LDS-free gemm1 with pre-converted bf16 Wt read from L2; (3) wave-
// vectorized row_ptr/dinv metadata. Aggregate rate is at the ~3.65 TB/s
// random-64B fabric floor (R6/R8/R9 all identical) — not touched further.

#define N_NODES 100000
#define N_EDGES 1000000
#define N_LABEL 200000
#define D_FEAT 128
#define BM 128

typedef short bf16x8 __attribute__((ext_vector_type(8)));
typedef float f32x4 __attribute__((ext_vector_type(4)));

// ---- bf16 helpers (RNE) ----
__device__ inline unsigned int f2bf(float x) {
    unsigned int u = __float_as_uint(x);
    return (u + 0x7FFFu + ((u >> 16) & 1u)) >> 16;
}
__device__ inline unsigned int bf16pack(float a, float b) {
    return f2bf(a) | (f2bf(b) << 16);
}
__device__ inline float bflo(unsigned int u) { return __uint_as_float(u << 16); }
__device__ inline float bfhi(unsigned int u) { return __uint_as_float(u & 0xFFFF0000u); }

// ---------------- degree histogram (int atomics) ----------------
__global__ void deg_hist(const int* __restrict__ dst, int* __restrict__ counts) {
    int e = blockIdx.x * 256 + threadIdx.x;
    if (e < N_EDGES) atomicAdd(&counts[dst[e]], 1);
}

// ---------------- scan_reduce + dinv fused ----------------
__global__ __launch_bounds__(256) void scan_reduce(const int* __restrict__ counts,
                                                   int* __restrict__ bsums,
                                                   float* __restrict__ dinv) {
    __shared__ int s[256];
    int t = threadIdx.x;
    int base = blockIdx.x * 1024 + t * 4;
    int sum = 0;
#pragma unroll
    for (int j = 0; j < 4; ++j) {
        int idx = base + j;
        if (idx < N_NODES) {
            int c = counts[idx];
            sum += c;
            dinv[idx] = rsqrtf((float)(c + 1));  // +1 self-loop
        }
    }
    s[t] = sum;
    __syncthreads();
    for (int off = 128; off > 0; off >>= 1) {
        if (t < off) s[t] += s[t + off];
        __syncthreads();
    }
    if (t == 0) bsums[blockIdx.x] = s[0];
}

// ---------------- scan_apply: block computes own bsums-prefix itself ----------------
__global__ __launch_bounds__(256) void scan_apply(const int* __restrict__ counts,
                                                  const int* __restrict__ bsums,
                                                  int* __restrict__ row_ptr) {
    __shared__ int s[256];
    int t = threadIdx.x;
    s[t] = (t < blockIdx.x) ? bsums[t] : 0;
    __syncthreads();
    for (int off = 128; off > 0; off >>= 1) {
        if (t < off) s[t] += s[t + off];
        __syncthreads();
    }
    int block_base = s[0];
    __syncthreads();

    int base = blockIdx.x * 1024 + t * 4;
    int v[4];
    int sum = 0;
#pragma unroll
    for (int j = 0; j < 4; ++j) {
        int idx = base + j;
        v[j] = (idx < N_NODES) ? counts[idx] : 0;
        sum += v[j];
    }
    s[t] = sum;
    __syncthreads();
    for (int off = 1; off < 256; off <<= 1) {
        int a = (t >= off) ? s[t - off] : 0;
        __syncthreads();
        s[t] += a;
        __syncthreads();
    }
    int excl = ((t == 0) ? 0 : s[t - 1]) + block_base;
    int run = 0;
#pragma unroll
    for (int j = 0; j < 4; ++j) {
        int idx = base + j;
        if (idx < N_NODES) row_ptr[idx] = excl + run;
        run += v[j];
    }
    if (blockIdx.x == 0 && t == 0) row_ptr[N_NODES] = N_EDGES;
}

// ---------------- bucket fill via atomicSub on counts ----------------
__global__ void fill_csr(const int* __restrict__ src, const int* __restrict__ dst,
                         const float* __restrict__ dinv, const int* __restrict__ row_ptr,
                         int* __restrict__ counts, int2* __restrict__ packed) {
    int e = blockIdx.x * 256 + threadIdx.x;
    if (e >= N_EDGES) return;
    int s = src[e], d = dst[e];
    int pos = row_ptr[d] + atomicSub(&counts[d], 1) - 1;
    float norm = dinv[s] * dinv[d];
    packed[pos] = make_int2(s, __float_as_int(norm));
}

// ---------------- W (fp32 [k][n]) -> Wt (bf16 [n][k]) ----------------
__global__ void w2bf(const float* __restrict__ W1, const float* __restrict__ W2,
                     unsigned short* __restrict__ Wt1, unsigned short* __restrict__ Wt2) {
    int i = blockIdx.x * 256 + threadIdx.x;  // 0..32767
    const float* W = (i < 16384) ? W1 : W2;
    unsigned short* Wt = (i < 16384) ? Wt1 : Wt2;
    int j = i & 16383;
    int n = j >> 7, k = j & 127;
    Wt[j] = (unsigned short)f2bf(W[(size_t)k * 128 + n]);
}

// ---------------- gemm1: H1 = feat(fp32) @ W1, LDS-free MFMA ----------------
__global__ __launch_bounds__(256) void gemm_mfma_f32(const float* __restrict__ X,
                                                     const unsigned short* __restrict__ Wt,
                                                     unsigned int* __restrict__ Y,
                                                     int nrows) {
    int t = threadIdx.x;
    int wv = t >> 6;
    int lane = t & 63, l16 = lane & 15, quad = lane >> 4;
    int rbase = blockIdx.x * BM + wv * 32;
    if (rbase >= nrows) return;

    f32x4 acc[2][8];
#pragma unroll
    for (int rt = 0; rt < 2; ++rt)
#pragma unroll
        for (int nt = 0; nt < 8; ++nt) acc[rt][nt] = (f32x4){0.f, 0.f, 0.f, 0.f};

#pragma unroll
    for (int kb = 0; kb < 4; ++kb) {
        bf16x8 af[2];
#pragma unroll
        for (int rt = 0; rt < 2; ++rt) {
            int row = rbase + rt * 16 + l16;
            if (row > nrows - 1) row = nrows - 1;
            float4 fa = ((const float4*)X)[(size_t)row * 32 + kb * 8 + quad * 2];
            float4 fb = ((const float4*)X)[(size_t)row * 32 + kb * 8 + quad * 2 + 1];
            union { uint4 u; bf16x8 v; } cv;
            cv.u.x = bf16pack(fa.x, fa.y);
            cv.u.y = bf16pack(fa.z, fa.w);
            cv.u.z = bf16pack(fb.x, fb.y);
            cv.u.w = bf16pack(fb.z, fb.w);
            af[rt] = cv.v;
        }
        bf16x8 bfr[8];
#pragma unroll
        for (int nt = 0; nt < 8; ++nt)
            bfr[nt] = *(const bf16x8*)&Wt[(size_t)(nt * 16 + l16) * 128 + kb * 32 + quad * 8];
#pragma unroll
        for (int rt = 0; rt < 2; ++rt)
#pragma unroll
            for (int nt = 0; nt < 8; ++nt)
                acc[rt][nt] = __builtin_amdgcn_mfma_f32_16x16x32_bf16(
                    af[rt], bfr[nt], acc[rt][nt], 0, 0, 0);
    }

    short* Ys = (short*)Y;
#pragma unroll
    for (int rt = 0; rt < 2; ++rt)
#pragma unroll
        for (int reg = 0; reg < 4; ++reg) {
            int row = rbase + rt * 16 + quad * 4 + reg;
            if (row < nrows) {
#pragma unroll
                for (int nt = 0; nt < 8; ++nt)
                    Ys[(size_t)row * 128 + nt * 16 + l16] = (short)f2bf(acc[rt][nt][reg]);
            }
        }
}

// ---------------- fused agg1 + gemm2 ----------------
// Each wave: aggregate 32 nodes (2/iter, 16 gathers in flight) + relu+bias ->
// private LDS tile (XOR-swizzled 16B chunks); then MFMA vs Wt2 (global, L2);
// store H2. No __syncthreads (per-wave LDS region, same-wave ds ordering).
__global__ __launch_bounds__(256) void agg_gemm(const unsigned int* __restrict__ Hb,
                                                const int2* __restrict__ packed,
                                                const int* __restrict__ row_ptr,
                                                const float* __restrict__ dinv,
                                                const float* __restrict__ bias,
                                                const unsigned short* __restrict__ Wt,
                                                unsigned int* __restrict__ Y,
                                                int nrows) {
    __shared__ short Xs[4][32 * 128];  // 8 KB per wave
    int wv = threadIdx.x >> 6;
    int lane = threadIdx.x & 63, l16 = lane & 15, quad = lane >> 4;
    int nodeBase = blockIdx.x * BM + wv * 32;
    if (nodeBase >= nrows) return;

    // wave-vectorized metadata: row_ptr[nodeBase+0..32], dinv[nodeBase+0..31]
    int rp = 0;
    if (lane <= 32 && nodeBase + lane <= nrows) rp = row_ptr[nodeBase + lane];
    float dvl = 0.f;
    if (lane < 32 && nodeBase + lane < nrows) dvl = dinv[nodeBase + lane];

    float2 bb = ((const float2*)bias)[lane];
    unsigned int* xw = (unsigned int*)Xs[wv];

    for (int it = 0; it < 16; ++it) {
        int v0 = nodeBase + it * 2, v1 = v0 + 1;
        bool h0 = v0 < nrows, h1 = v1 < nrows;
        int st0 = __shfl(rp, it * 2), en0 = h0 ? __shfl(rp, it * 2 + 1) : 0;
        int st1 = __shfl(rp, it * 2 + 1), en1 = h1 ? __shfl(rp, it * 2 + 2) : st1;
        float dv0 = __shfl(dvl, it * 2), d20 = dv0 * dv0;
        float dv1 = __shfl(dvl, it * 2 + 1), d21 = dv1 * dv1;

        unsigned int su0 = h0 ? Hb[(size_t)v0 * 64 + lane] : 0u;
        unsigned int su1 = h1 ? Hb[(size_t)v1 * 64 + lane] : 0u;
        float a0 = d20 * bflo(su0), a1 = d20 * bfhi(su0);
        float b0 = d21 * bflo(su1), b1 = d21 * bfhi(su1);

        for (int c0 = st0, c1 = st1; c0 < en0 || c1 < en1; c0 += 32, c1 += 32) {
            int n0 = en0 - c0; n0 = n0 < 0 ? 0 : (n0 > 32 ? 32 : n0);
            int n1 = en1 - c1; n1 = n1 < 0 ? 0 : (n1 > 32 ? 32 : n1);
            int2 p = make_int2(0, 0);
            if (lane < 32) {
                if (lane < n0) p = packed[c0 + lane];
            } else {
                if (lane - 32 < n1) p = packed[c1 + lane - 32];
            }
            int nmax = n0 > n1 ? n0 : n1;
            for (int j = 0; j < nmax; j += 8) {
                int sA[8], sB[8];
                float nrA[8], nrB[8];
#pragma unroll
                for (int q = 0; q < 8; ++q) {
                    sA[q] = __shfl(p.x, j + q);
                    nrA[q] = __int_as_float(__shfl(p.y, j + q));
                    sB[q] = __shfl(p.x, 32 + j + q);
                    nrB[q] = __int_as_float(__shfl(p.y, 32 + j + q));
                }
                unsigned int uA[8], uB[8];
#pragma unroll
                for (int q = 0; q < 8; ++q) {
                    uA[q] = Hb[(size_t)sA[q] * 64 + lane];
                    uB[q] = Hb[(size_t)sB[q] * 64 + lane];
                }
#pragma unroll
                for (int q = 0; q < 8; ++q) {
                    a0 = fmaf(nrA[q], bflo(uA[q]), a0);
                    a1 = fmaf(nrA[q], bfhi(uA[q]), a1);
                    b0 = fmaf(nrB[q], bflo(uB[q]), b0);
                    b1 = fmaf(nrB[q], bfhi(uB[q]), b1);
                }
            }
        }
        // relu + bias (layer-1 epilogue), write rows to swizzled LDS tile
        a0 = fmaxf(a0 + bb.x, 0.f);
        a1 = fmaxf(a1 + bb.y, 0.f);
        b0 = fmaxf(b0 + bb.x, 0.f);
        b1 = fmaxf(b1 + bb.y, 0.f);
        int r0 = it * 2, r1 = r0 + 1;
        xw[r0 * 64 + ((((lane >> 2) ^ (r0 & 15)) << 2) | (lane & 3))] = bf16pack(a0, a1);
        xw[r1 * 64 + ((((lane >> 2) ^ (r1 & 15)) << 2) | (lane & 3))] = bf16pack(b0, b1);
    }

    // ---- MFMA phase: rows = this wave's 32 nodes ----
    f32x4 acc[2][8];
#pragma unroll
    for (int rt = 0; rt < 2; ++rt)
#pragma unroll
        for (int nt = 0; nt < 8; ++nt) acc[rt][nt] = (f32x4){0.f, 0.f, 0.f, 0.f};

#pragma unroll
    for (int kb = 0; kb < 4; ++kb) {
        bf16x8 af[2];
#pragma unroll
        for (int rt = 0; rt < 2; ++rt) {
            int r = rt * 16 + l16;
            af[rt] = *(const bf16x8*)&Xs[wv][r * 128 + (((kb * 4 + quad) ^ (r & 15)) << 3)];
        }
        bf16x8 bfr[8];
#pragma unroll
        for (int nt = 0; nt < 8; ++nt)
            bfr[nt] = *(const bf16x8*)&Wt[(size_t)(nt * 16 + l16) * 128 + kb * 32 + quad * 8];
#pragma unroll
        for (int rt = 0; rt < 2; ++rt)
#pragma unroll
            for (int nt = 0; nt < 8; ++nt)
                acc[rt][nt] = __builtin_amdgcn_mfma_f32_16x16x32_bf16(
                    af[rt], bfr[nt], acc[rt][nt], 0, 0, 0);
    }

    short* Ys = (short*)Y;
#pragma unroll
    for (int rt = 0; rt < 2; ++rt)
#pragma unroll
        for (int reg = 0; reg < 4; ++reg) {
            int row = nodeBase + rt * 16 + quad * 4 + reg;
            if (row < nrows) {
#pragma unroll
                for (int nt = 0; nt < 8; ++nt)
                    Ys[(size_t)row * 128 + nt * 16 + l16] = (short)f2bf(acc[rt][nt][reg]);
            }
        }
}

// ---------------- gather-aggregate (layer 2): 2 nodes/wave, 16 in flight ----
__global__ __launch_bounds__(256) void aggregate2(const unsigned int* __restrict__ Hb,
                                                  const int2* __restrict__ packed,
                                                  const int* __restrict__ row_ptr,
                                                  const float* __restrict__ dinv,
                                                  unsigned int* __restrict__ Xb) {
    int v0 = blockIdx.x * 8 + (threadIdx.x >> 6) * 2;
    int v1 = v0 + 1;
    int lane = threadIdx.x & 63;
    if (v0 >= N_NODES) return;
    bool h1 = (v1 < N_NODES);

    int st0 = row_ptr[v0], en0 = row_ptr[v0 + 1];
    int st1 = h1 ? row_ptr[v1] : 0, en1 = h1 ? row_ptr[v1 + 1] : 0;
    float dv0 = dinv[v0], d20 = dv0 * dv0;
    float dv1 = h1 ? dinv[v1] : 0.f, d21 = dv1 * dv1;

    unsigned int su0 = Hb[(size_t)v0 * 64 + lane];
    float a0 = d20 * bflo(su0), a1 = d20 * bfhi(su0);
    unsigned int su1 = h1 ? Hb[(size_t)v1 * 64 + lane] : 0u;
    float b0 = d21 * bflo(su1), b1 = d21 * bfhi(su1);

    for (int c0 = st0, c1 = st1; c0 < en0 || c1 < en1; c0 += 32, c1 += 32) {
        int n0 = en0 - c0; n0 = n0 < 0 ? 0 : (n0 > 32 ? 32 : n0);
        int n1 = en1 - c1; n1 = n1 < 0 ? 0 : (n1 > 32 ? 32 : n1);
        int2 p = make_int2(0, 0);
        if (lane < 32) {
            if (lane < n0) p = packed[c0 + lane];
        } else {
            if (lane - 32 < n1) p = packed[c1 + lane - 32];
        }
        int nmax = n0 > n1 ? n0 : n1;
        for (int j = 0; j < nmax; j += 8) {
            int sA[8], sB[8];
            float nrA[8], nrB[8];
#pragma unroll
            for (int q = 0; q < 8; ++q) {
                sA[q] = __shfl(p.x, j + q);
                nrA[q] = __int_as_float(__shfl(p.y, j + q));
                sB[q] = __shfl(p.x, 32 + j + q);
                nrB[q] = __int_as_float(__shfl(p.y, 32 + j + q));
            }
            unsigned int uA[8], uB[8];
#pragma unroll
            for (int q = 0; q < 8; ++q) {
                uA[q] = Hb[(size_t)sA[q] * 64 + lane];
                uB[q] = Hb[(size_t)sB[q] * 64 + lane];
            }
#pragma unroll
            for (int q = 0; q < 8; ++q) {
                a0 = fmaf(nrA[q], bflo(uA[q]), a0);
                a1 = fmaf(nrA[q], bfhi(uA[q]), a1);
                b0 = fmaf(nrB[q], bflo(uB[q]), b0);
                b1 = fmaf(nrB[q], bfhi(uB[q]), b1);
            }
        }
    }

    Xb[(size_t)v0 * 64 + lane] = bf16pack(a0, a1);
    if (h1) Xb[(size_t)v1 * 64 + lane] = bf16pack(b0, b1);
}

// ---------------- edge scoring: 4 label edges per wave ----------------
__global__ __launch_bounds__(256) void score_kernel(const int* __restrict__ ea,
                                                    const int* __restrict__ eb,
                                                    const unsigned int* __restrict__ Xb,
                                                    const float* __restrict__ bias,
                                                    float* __restrict__ out) {
    int wbase = (blockIdx.x * 4 + (threadIdx.x >> 6)) * 4;
    int lane = threadIdx.x & 63;
    if (wbase >= N_LABEL) return;
    int ne = N_LABEL - wbase;
    if (ne > 4) ne = 4;
    float2 bb = ((const float2*)bias)[lane];

    unsigned int ua[4], ub[4];
#pragma unroll
    for (int e = 0; e < 4; ++e)
        if (e < ne) {
            int ia = ea[wbase + e], ib = eb[wbase + e];
            ua[e] = Xb[(size_t)ia * 64 + lane];
            ub[e] = Xb[(size_t)ib * 64 + lane];
        }
#pragma unroll
    for (int e = 0; e < 4; ++e)
        if (e < ne) {
            float p = (bflo(ua[e]) + bb.x) * (bflo(ub[e]) + bb.x) +
                      (bfhi(ua[e]) + bb.y) * (bfhi(ub[e]) + bb.y);
#pragma unroll
            for (int off = 32; off > 0; off >>= 1) p += __shfl_down(p, off);
            if (lane == 0) out[wbase + e] = p;
        }
}

extern "C" void kernel_launch(void* const* d_in, const int* in_sizes, int n_in,
                              void* d_out, int out_size, void* d_ws, size_t ws_size,
                              hipStream_t stream) {
    const float* feat = (const float*)d_in[0];
    const int* ei = (const int*)d_in[1];
    const int* eli = (const int*)d_in[2];
    const float* W1 = (const float*)d_in[3];
    const float* b1 = (const float*)d_in[4];
    const float* W2 = (const float*)d_in[5];
    const float* b2 = (const float*)d_in[6];
    float* out = (float*)d_out;

    const int* src = ei;
    const int* dst = ei + N_EDGES;
    const int* la = eli;
    const int* lb = eli + N_LABEL;

    // ---- workspace layout (every section multiple of 16 B) ----
    int* counts = (int*)d_ws;                        // N ints
    int* row_ptr = counts + N_NODES;                 // N+4 ints (N+1 used)
    int* bsums = row_ptr + N_NODES + 4;              // 128
    float* dinv = (float*)(bsums + 128);             // N
    unsigned short* wt1 = (unsigned short*)(dinv + N_NODES);  // 16384 ushort (32 KB)
    unsigned short* wt2 = wt1 + 16384;                        // 16384 ushort
    int2* packed = (int2*)(wt2 + 16384);                      // E int2 (8 MB)
    unsigned int* Hb = (unsigned int*)(packed + N_EDGES);     // N*64 uints
    unsigned int* Xb = Hb + (size_t)N_NODES * 64;             // N*64 uints

    const int TB = 256;
    int gE = (N_EDGES + TB - 1) / TB;
    int gScan = (N_NODES + 1023) / 1024;     // 98
    int gGemm = (N_NODES + BM - 1) / BM;     // 782
    int gAgg = (N_NODES + 7) / 8;            // 12500
    int gScore = (N_LABEL + 15) / 16;        // 12500

    hipMemsetAsync(counts, 0, N_NODES * sizeof(int), stream);

    // CSR build + weight conversion
    deg_hist<<<gE, TB, 0, stream>>>(dst, counts);
    scan_reduce<<<gScan, TB, 0, stream>>>(counts, bsums, dinv);
    scan_apply<<<gScan, TB, 0, stream>>>(counts, bsums, row_ptr);
    fill_csr<<<gE, TB, 0, stream>>>(src, dst, dinv, row_ptr, counts, packed);
    w2bf<<<128, TB, 0, stream>>>(W1, W2, wt1, wt2);

    // layer 1 transform: H1 = feat @ W1
    gemm_mfma_f32<<<gGemm, TB, 0, stream>>>(feat, wt1, Hb, N_NODES);

    // fused: X1 = relu(agg(H1)+b1); H2 = X1 @ W2  (X1 never materialized)
    agg_gemm<<<gGemm, TB, 0, stream>>>(Hb, packed, row_ptr, dinv, b1, wt2, Xb, N_NODES);

    // layer 2 aggregate: X2 = agg(H2)   (note: Xb holds H2, Hb receives X2)
    aggregate2<<<gAgg, TB, 0, stream>>>(Xb, packed, row_ptr, dinv, Hb);

    // scoring (b2 folded in)
    score_kernel<<<gScore, TB, 0, stream>>>(la, lb, Hb, b2, out);
}

// Round 11
// 375.008 us; speedup vs baseline: 1.0543x; 1.0543x over previous
//
#include <hip/hip_runtime.h>
#include <hip/hip_bf16.h>

// GCN link-prediction: 2x GCNConv(128->128) + edge dot scoring.
// Round 11: revert R10's fusion (gather-phase occupancy collapse: 18.6% occ,
// 1.9 TB/s vs 3.65 floor). R9 skeleton + keep w2bf & LDS-free MFMA gemms.
// LESSON: never couple a latency-bound gather loop with a register/LDS-heavy
// compute phase — gather rate scales with resident waves.

#define N_NODES 100000
#define N_EDGES 1000000
#define N_LABEL 200000
#define D_FEAT 128
#define BM 128

typedef short bf16x8 __attribute__((ext_vector_type(8)));
typedef float f32x4 __attribute__((ext_vector_type(4)));

// ---- bf16 helpers (RNE) ----
__device__ inline unsigned int f2bf(float x) {
    unsigned int u = __float_as_uint(x);
    return (u + 0x7FFFu + ((u >> 16) & 1u)) >> 16;
}
__device__ inline unsigned int bf16pack(float a, float b) {
    return f2bf(a) | (f2bf(b) << 16);
}
__device__ inline float bflo(unsigned int u) { return __uint_as_float(u << 16); }
__device__ inline float bfhi(unsigned int u) { return __uint_as_float(u & 0xFFFF0000u); }

// ---------------- degree histogram (int atomics) ----------------
__global__ void deg_hist(const int* __restrict__ dst, int* __restrict__ counts) {
    int e = blockIdx.x * 256 + threadIdx.x;
    if (e < N_EDGES) atomicAdd(&counts[dst[e]], 1);
}

// ---------------- scan_reduce + dinv fused ----------------
__global__ __launch_bounds__(256) void scan_reduce(const int* __restrict__ counts,
                                                   int* __restrict__ bsums,
                                                   float* __restrict__ dinv) {
    __shared__ int s[256];
    int t = threadIdx.x;
    int base = blockIdx.x * 1024 + t * 4;
    int sum = 0;
#pragma unroll
    for (int j = 0; j < 4; ++j) {
        int idx = base + j;
        if (idx < N_NODES) {
            int c = counts[idx];
            sum += c;
            dinv[idx] = rsqrtf((float)(c + 1));  // +1 self-loop
        }
    }
    s[t] = sum;
    __syncthreads();
    for (int off = 128; off > 0; off >>= 1) {
        if (t < off) s[t] += s[t + off];
        __syncthreads();
    }
    if (t == 0) bsums[blockIdx.x] = s[0];
}

// ---------------- scan_apply: block computes own bsums-prefix itself ----------------
__global__ __launch_bounds__(256) void scan_apply(const int* __restrict__ counts,
                                                  const int* __restrict__ bsums,
                                                  int* __restrict__ row_ptr) {
    __shared__ int s[256];
    int t = threadIdx.x;
    s[t] = (t < blockIdx.x) ? bsums[t] : 0;
    __syncthreads();
    for (int off = 128; off > 0; off >>= 1) {
        if (t < off) s[t] += s[t + off];
        __syncthreads();
    }
    int block_base = s[0];
    __syncthreads();

    int base = blockIdx.x * 1024 + t * 4;
    int v[4];
    int sum = 0;
#pragma unroll
    for (int j = 0; j < 4; ++j) {
        int idx = base + j;
        v[j] = (idx < N_NODES) ? counts[idx] : 0;
        sum += v[j];
    }
    s[t] = sum;
    __syncthreads();
    for (int off = 1; off < 256; off <<= 1) {
        int a = (t >= off) ? s[t - off] : 0;
        __syncthreads();
        s[t] += a;
        __syncthreads();
    }
    int excl = ((t == 0) ? 0 : s[t - 1]) + block_base;
    int run = 0;
#pragma unroll
    for (int j = 0; j < 4; ++j) {
        int idx = base + j;
        if (idx < N_NODES) row_ptr[idx] = excl + run;
        run += v[j];
    }
    if (blockIdx.x == 0 && t == 0) row_ptr[N_NODES] = N_EDGES;
}

// ---------------- bucket fill via atomicSub on counts ----------------
__global__ void fill_csr(const int* __restrict__ src, const int* __restrict__ dst,
                         const float* __restrict__ dinv, const int* __restrict__ row_ptr,
                         int* __restrict__ counts, int2* __restrict__ packed) {
    int e = blockIdx.x * 256 + threadIdx.x;
    if (e >= N_EDGES) return;
    int s = src[e], d = dst[e];
    int pos = row_ptr[d] + atomicSub(&counts[d], 1) - 1;
    float norm = dinv[s] * dinv[d];
    packed[pos] = make_int2(s, __float_as_int(norm));
}

// ---------------- W (fp32 [k][n]) -> Wt (bf16 [n][k]) ----------------
__global__ void w2bf(const float* __restrict__ W1, const float* __restrict__ W2,
                     unsigned short* __restrict__ Wt1, unsigned short* __restrict__ Wt2) {
    int i = blockIdx.x * 256 + threadIdx.x;  // 0..32767
    const float* W = (i < 16384) ? W1 : W2;
    unsigned short* Wt = (i < 16384) ? Wt1 : Wt2;
    int j = i & 16383;
    int n = j >> 7, k = j & 127;
    Wt[j] = (unsigned short)f2bf(W[(size_t)k * 128 + n]);
}

// ---------------- LDS-free MFMA GEMM: Y_bf16 = X @ Wt^T ----------------
// 4 waves/block, wave = 32 rows x 128 cols. B-frags stream from L2-resident
// Wt (bf16 [n][k]); A-frags direct from global (fp32 or bf16).
template <bool BF16_IN>
__global__ __launch_bounds__(256) void gemm_mfma(const void* __restrict__ Xv,
                                                 const unsigned short* __restrict__ Wt,
                                                 unsigned int* __restrict__ Y,
                                                 int nrows) {
    int t = threadIdx.x;
    int wv = t >> 6;
    int lane = t & 63, l16 = lane & 15, quad = lane >> 4;
    int rbase = blockIdx.x * BM + wv * 32;
    if (rbase >= nrows) return;

    f32x4 acc[2][8];
#pragma unroll
    for (int rt = 0; rt < 2; ++rt)
#pragma unroll
        for (int nt = 0; nt < 8; ++nt) acc[rt][nt] = (f32x4){0.f, 0.f, 0.f, 0.f};

#pragma unroll
    for (int kb = 0; kb < 4; ++kb) {
        bf16x8 af[2];
#pragma unroll
        for (int rt = 0; rt < 2; ++rt) {
            int row = rbase + rt * 16 + l16;
            if (row > nrows - 1) row = nrows - 1;
            if constexpr (BF16_IN) {
                const unsigned int* Xb = (const unsigned int*)Xv;
                af[rt] = *(const bf16x8*)&Xb[(size_t)row * 64 + kb * 16 + quad * 4];
            } else {
                const float* X = (const float*)Xv;
                float4 fa = ((const float4*)X)[(size_t)row * 32 + kb * 8 + quad * 2];
                float4 fb = ((const float4*)X)[(size_t)row * 32 + kb * 8 + quad * 2 + 1];
                union { uint4 u; bf16x8 v; } cv;
                cv.u.x = bf16pack(fa.x, fa.y);
                cv.u.y = bf16pack(fa.z, fa.w);
                cv.u.z = bf16pack(fb.x, fb.y);
                cv.u.w = bf16pack(fb.z, fb.w);
                af[rt] = cv.v;
            }
        }
        bf16x8 bfr[8];
#pragma unroll
        for (int nt = 0; nt < 8; ++nt)
            bfr[nt] = *(const bf16x8*)&Wt[(size_t)(nt * 16 + l16) * 128 + kb * 32 + quad * 8];
#pragma unroll
        for (int rt = 0; rt < 2; ++rt)
#pragma unroll
            for (int nt = 0; nt < 8; ++nt)
                acc[rt][nt] = __builtin_amdgcn_mfma_f32_16x16x32_bf16(
                    af[rt], bfr[nt], acc[rt][nt], 0, 0, 0);
    }

    short* Ys = (short*)Y;
#pragma unroll
    for (int rt = 0; rt < 2; ++rt)
#pragma unroll
        for (int reg = 0; reg < 4; ++reg) {
            int row = rbase + rt * 16 + quad * 4 + reg;
            if (row < nrows) {
#pragma unroll
                for (int nt = 0; nt < 8; ++nt)
                    Ys[(size_t)row * 128 + nt * 16 + l16] = (short)f2bf(acc[rt][nt][reg]);
            }
        }
}

// ---------------- gather-aggregate: 2 nodes/wave, 16 gathers in flight ----
template <bool RELU>
__global__ __launch_bounds__(256) void aggregate(const unsigned int* __restrict__ Hb,
                                                 const int2* __restrict__ packed,
                                                 const int* __restrict__ row_ptr,
                                                 const float* __restrict__ dinv,
                                                 const float* __restrict__ bias,
                                                 unsigned int* __restrict__ Xb) {
    int v0 = blockIdx.x * 8 + (threadIdx.x >> 6) * 2;
    int v1 = v0 + 1;
    int lane = threadIdx.x & 63;
    if (v0 >= N_NODES) return;
    bool h1 = (v1 < N_NODES);

    int st0 = row_ptr[v0], en0 = row_ptr[v0 + 1];
    int st1 = h1 ? row_ptr[v1] : 0, en1 = h1 ? row_ptr[v1 + 1] : 0;
    float dv0 = dinv[v0], d20 = dv0 * dv0;
    float dv1 = h1 ? dinv[v1] : 0.f, d21 = dv1 * dv1;

    unsigned int su0 = Hb[(size_t)v0 * 64 + lane];
    float a0 = d20 * bflo(su0), a1 = d20 * bfhi(su0);
    unsigned int su1 = h1 ? Hb[(size_t)v1 * 64 + lane] : 0u;
    float b0 = d21 * bflo(su1), b1 = d21 * bfhi(su1);

    for (int c0 = st0, c1 = st1; c0 < en0 || c1 < en1; c0 += 32, c1 += 32) {
        int n0 = en0 - c0; n0 = n0 < 0 ? 0 : (n0 > 32 ? 32 : n0);
        int n1 = en1 - c1; n1 = n1 < 0 ? 0 : (n1 > 32 ? 32 : n1);
        int2 p = make_int2(0, 0);
        if (lane < 32) {
            if (lane < n0) p = packed[c0 + lane];
        } else {
            if (lane - 32 < n1) p = packed[c1 + lane - 32];
        }
        int nmax = n0 > n1 ? n0 : n1;
        for (int j = 0; j < nmax; j += 8) {
            int sA[8], sB[8];
            float nrA[8], nrB[8];
#pragma unroll
            for (int q = 0; q < 8; ++q) {
                sA[q] = __shfl(p.x, j + q);
                nrA[q] = __int_as_float(__shfl(p.y, j + q));
                sB[q] = __shfl(p.x, 32 + j + q);
                nrB[q] = __int_as_float(__shfl(p.y, 32 + j + q));
            }
            unsigned int uA[8], uB[8];
#pragma unroll
            for (int q = 0; q < 8; ++q) {
                uA[q] = Hb[(size_t)sA[q] * 64 + lane];
                uB[q] = Hb[(size_t)sB[q] * 64 + lane];
            }
#pragma unroll
            for (int q = 0; q < 8; ++q) {
                a0 = fmaf(nrA[q], bflo(uA[q]), a0);
                a1 = fmaf(nrA[q], bfhi(uA[q]), a1);
                b0 = fmaf(nrB[q], bflo(uB[q]), b0);
                b1 = fmaf(nrB[q], bfhi(uB[q]), b1);
            }
        }
    }

    if (RELU) {
        float2 bb = ((const float2*)bias)[lane];
        a0 = fmaxf(a0 + bb.x, 0.f);
        a1 = fmaxf(a1 + bb.y, 0.f);
        b0 = fmaxf(b0 + bb.x, 0.f);
        b1 = fmaxf(b1 + bb.y, 0.f);
    }
    Xb[(size_t)v0 * 64 + lane] = bf16pack(a0, a1);
    if (h1) Xb[(size_t)v1 * 64 + lane] = bf16pack(b0, b1);
}

// ---------------- edge scoring: 4 label edges per wave ----------------
__global__ __launch_bounds__(256) void score_kernel(const int* __restrict__ ea,
                                                    const int* __restrict__ eb,
                                                    const unsigned int* __restrict__ Xb,
                                                    const float* __restrict__ bias,
                                                    float* __restrict__ out) {
    int wbase = (blockIdx.x * 4 + (threadIdx.x >> 6)) * 4;
    int lane = threadIdx.x & 63;
    if (wbase >= N_LABEL) return;
    int ne = N_LABEL - wbase;
    if (ne > 4) ne = 4;
    float2 bb = ((const float2*)bias)[lane];

    unsigned int ua[4], ub[4];
#pragma unroll
    for (int e = 0; e < 4; ++e)
        if (e < ne) {
            int ia = ea[wbase + e], ib = eb[wbase + e];
            ua[e] = Xb[(size_t)ia * 64 + lane];
            ub[e] = Xb[(size_t)ib * 64 + lane];
        }
#pragma unroll
    for (int e = 0; e < 4; ++e)
        if (e < ne) {
            float p = (bflo(ua[e]) + bb.x) * (bflo(ub[e]) + bb.x) +
                      (bfhi(ua[e]) + bb.y) * (bfhi(ub[e]) + bb.y);
#pragma unroll
            for (int off = 32; off > 0; off >>= 1) p += __shfl_down(p, off);
            if (lane == 0) out[wbase + e] = p;
        }
}

extern "C" void kernel_launch(void* const* d_in, const int* in_sizes, int n_in,
                              void* d_out, int out_size, void* d_ws, size_t ws_size,
                              hipStream_t stream) {
    const float* feat = (const float*)d_in[0];
    const int* ei = (const int*)d_in[1];
    const int* eli = (const int*)d_in[2];
    const float* W1 = (const float*)d_in[3];
    const float* b1 = (const float*)d_in[4];
    const float* W2 = (const float*)d_in[5];
    const float* b2 = (const float*)d_in[6];
    float* out = (float*)d_out;

    const int* src = ei;
    const int* dst = ei + N_EDGES;
    const int* la = eli;
    const int* lb = eli + N_LABEL;

    int* counts = (int*)d_ws;                        // N ints
    int* row_ptr = counts + N_NODES;                 // N+4 ints
    int* bsums = row_ptr + N_NODES + 4;              // 128
    float* dinv = (float*)(bsums + 128);             // N
    unsigned short* wt1 = (unsigned short*)(dinv + N_NODES);  // 16384 ushort
    unsigned short* wt2 = wt1 + 16384;                        // 16384 ushort
    int2* packed = (int2*)(wt2 + 16384);                      // E int2 (8 MB)
    unsigned int* Hb = (unsigned int*)(packed + N_EDGES);     // N*64 uints
    unsigned int* Xb = Hb + (size_t)N_NODES * 64;             // N*64 uints

    const int TB = 256;
    int gE = (N_EDGES + TB - 1) / TB;
    int gScan = (N_NODES + 1023) / 1024;     // 98
    int gGemm = (N_NODES + BM - 1) / BM;     // 782
    int gAgg = (N_NODES + 7) / 8;            // 12500
    int gScore = (N_LABEL + 15) / 16;        // 12500

    hipMemsetAsync(counts, 0, N_NODES * sizeof(int), stream);

    // CSR build + weight conversion
    deg_hist<<<gE, TB, 0, stream>>>(dst, counts);
    scan_reduce<<<gScan, TB, 0, stream>>>(counts, bsums, dinv);
    scan_apply<<<gScan, TB, 0, stream>>>(counts, bsums, row_ptr);
    fill_csr<<<gE, TB, 0, stream>>>(src, dst, dinv, row_ptr, counts, packed);
    w2bf<<<128, TB, 0, stream>>>(W1, W2, wt1, wt2);

    // layer 1
    gemm_mfma<false><<<gGemm, TB, 0, stream>>>(feat, wt1, Hb, N_NODES);
    aggregate<true><<<gAgg, TB, 0, stream>>>(Hb, packed, row_ptr, dinv, b1, Xb);

    // layer 2
    gemm_mfma<true><<<gGemm, TB, 0, stream>>>(Xb, wt2, Hb, N_NODES);
    aggregate<false><<<gAgg, TB, 0, stream>>>(Hb, packed, row_ptr, dinv, b2, Xb);

    // scoring (b2 folded in)
    score_kernel<<<gScore, TB, 0, stream>>>(la, lb, Xb, b2, out);
}

// Round 12
// 349.121 us; speedup vs baseline: 1.1325x; 1.0741x over previous
//
#include <hip/hip_runtime.h>
#include <hip/hip_bf16.h>

// GCN link-prediction: 2x GCNConv(128->128) + edge dot scoring.
// Round 12: R9 skeleton (best, 353.5us) + bf16-W LDS staging (halves gemm
// staging bytes; w2bf folded into deg_hist launch). LESSONS BANKED:
// - aggregate gather: keep meta in registers (coalesced+shfl), 8-16 deep MLP,
//   high occupancy -> pinned at ~3.65 TB/s random-64B fabric floor.
// - never fuse latency-bound gather with reg/LDS-heavy MFMA (R10: occ collapse).
// - never read MFMA B-frags strided from global: 16B/64B line waste (R11).

#define N_NODES 100000
#define N_EDGES 1000000
#define N_LABEL 200000
#define D_FEAT 128
#define BM 128

typedef short bf16x8 __attribute__((ext_vector_type(8)));
typedef float f32x4 __attribute__((ext_vector_type(4)));

// ---- bf16 helpers (RNE) ----
__device__ inline unsigned int f2bf(float x) {
    unsigned int u = __float_as_uint(x);
    return (u + 0x7FFFu + ((u >> 16) & 1u)) >> 16;
}
__device__ inline unsigned int bf16pack(float a, float b) {
    return f2bf(a) | (f2bf(b) << 16);
}
__device__ inline float bflo(unsigned int u) { return __uint_as_float(u << 16); }
__device__ inline float bfhi(unsigned int u) { return __uint_as_float(u & 0xFFFF0000u); }

// ---------------- degree histogram + W->bf16 transpose (merged launch) ----------------
#define G_EDGE 3907  // ceil(1e6/256)
__global__ void deg_hist_w2bf(const int* __restrict__ dst, int* __restrict__ counts,
                              const float* __restrict__ W1, const float* __restrict__ W2,
                              unsigned short* __restrict__ Wt1,
                              unsigned short* __restrict__ Wt2) {
    int b = blockIdx.x;
    if (b < G_EDGE) {
        int e = b * 256 + threadIdx.x;
        if (e < N_EDGES) atomicAdd(&counts[dst[e]], 1);
    } else {
        int i = (b - G_EDGE) * 256 + threadIdx.x;  // 0..32767
        const float* W = (i < 16384) ? W1 : W2;
        unsigned short* Wt = (i < 16384) ? Wt1 : Wt2;
        int j = i & 16383;
        int n = j >> 7, k = j & 127;
        Wt[j] = (unsigned short)f2bf(W[(size_t)k * 128 + n]);
    }
}

// ---------------- scan_reduce + dinv fused ----------------
__global__ __launch_bounds__(256) void scan_reduce(const int* __restrict__ counts,
                                                   int* __restrict__ bsums,
                                                   float* __restrict__ dinv) {
    __shared__ int s[256];
    int t = threadIdx.x;
    int base = blockIdx.x * 1024 + t * 4;
    int sum = 0;
#pragma unroll
    for (int j = 0; j < 4; ++j) {
        int idx = base + j;
        if (idx < N_NODES) {
            int c = counts[idx];
            sum += c;
            dinv[idx] = rsqrtf((float)(c + 1));  // +1 self-loop
        }
    }
    s[t] = sum;
    __syncthreads();
    for (int off = 128; off > 0; off >>= 1) {
        if (t < off) s[t] += s[t + off];
        __syncthreads();
    }
    if (t == 0) bsums[blockIdx.x] = s[0];
}

// ---------------- scan_apply: block computes own bsums-prefix itself ----------------
__global__ __launch_bounds__(256) void scan_apply(const int* __restrict__ counts,
                                                  const int* __restrict__ bsums,
                                                  int* __restrict__ row_ptr) {
    __shared__ int s[256];
    int t = threadIdx.x;
    s[t] = (t < blockIdx.x) ? bsums[t] : 0;
    __syncthreads();
    for (int off = 128; off > 0; off >>= 1) {
        if (t < off) s[t] += s[t + off];
        __syncthreads();
    }
    int block_base = s[0];
    __syncthreads();

    int base = blockIdx.x * 1024 + t * 4;
    int v[4];
    int sum = 0;
#pragma unroll
    for (int j = 0; j < 4; ++j) {
        int idx = base + j;
        v[j] = (idx < N_NODES) ? counts[idx] : 0;
        sum += v[j];
    }
    s[t] = sum;
    __syncthreads();
    for (int off = 1; off < 256; off <<= 1) {
        int a = (t >= off) ? s[t - off] : 0;
        __syncthreads();
        s[t] += a;
        __syncthreads();
    }
    int excl = ((t == 0) ? 0 : s[t - 1]) + block_base;
    int run = 0;
#pragma unroll
    for (int j = 0; j < 4; ++j) {
        int idx = base + j;
        if (idx < N_NODES) row_ptr[idx] = excl + run;
        run += v[j];
    }
    if (blockIdx.x == 0 && t == 0) row_ptr[N_NODES] = N_EDGES;
}

// ---------------- bucket fill via atomicSub on counts ----------------
__global__ void fill_csr(const int* __restrict__ src, const int* __restrict__ dst,
                         const float* __restrict__ dinv, const int* __restrict__ row_ptr,
                         int* __restrict__ counts, int2* __restrict__ packed) {
    int e = blockIdx.x * 256 + threadIdx.x;
    if (e >= N_EDGES) return;
    int s = src[e], d = dst[e];
    int pos = row_ptr[d] + atomicSub(&counts[d], 1) - 1;
    float norm = dinv[s] * dinv[d];
    packed[pos] = make_int2(s, __float_as_int(norm));
}

// ---------------- MFMA GEMM, LDS-staged bf16 W ----------------
// Block: 128 rows x 128 cols, 4 waves. Stage pre-converted Wt (bf16 [n][k],
// 32 KB) into LDS with chunk-XOR swizzle (coalesced 16B chunks); A-frags
// direct from global; fp32 accumulate; bf16 store.
template <bool BF16_IN>
__global__ __launch_bounds__(256) void gemm128_mfma(const void* __restrict__ Xv,
                                                    const unsigned short* __restrict__ Wt,
                                                    unsigned int* __restrict__ Y,
                                                    int nrows) {
    __shared__ short Ws[128 * 128];  // 32 KB
    int t = threadIdx.x;

    // stage: 2048 16B chunks, coalesced global reads, swizzled LDS stores
#pragma unroll
    for (int i = 0; i < 8; ++i) {
        int c = i * 256 + t;
        int n = c >> 4, q = c & 15;
        uint4 v = *(const uint4*)&Wt[(size_t)n * 128 + q * 8];
        *(uint4*)&Ws[n * 128 + ((q ^ (n & 15)) << 3)] = v;
    }
    __syncthreads();

    int wv = t >> 6;
    int lane = t & 63, l16 = lane & 15, quad = lane >> 4;
    int rbase = blockIdx.x * BM + wv * 32;

    f32x4 acc[2][8];
#pragma unroll
    for (int rt = 0; rt < 2; ++rt)
#pragma unroll
        for (int nt = 0; nt < 8; ++nt) acc[rt][nt] = (f32x4){0.f, 0.f, 0.f, 0.f};

#pragma unroll
    for (int kb = 0; kb < 4; ++kb) {
        bf16x8 af[2];
#pragma unroll
        for (int rt = 0; rt < 2; ++rt) {
            int row = rbase + rt * 16 + l16;
            if (row > nrows - 1) row = nrows - 1;
            if constexpr (BF16_IN) {
                const unsigned int* Xb = (const unsigned int*)Xv;
                af[rt] = *(const bf16x8*)&Xb[(size_t)row * 64 + kb * 16 + quad * 4];
            } else {
                const float* X = (const float*)Xv;
                float4 fa = ((const float4*)X)[(size_t)row * 32 + kb * 8 + quad * 2];
                float4 fb = ((const float4*)X)[(size_t)row * 32 + kb * 8 + quad * 2 + 1];
                union { uint4 u; bf16x8 v; } cv;
                cv.u.x = bf16pack(fa.x, fa.y);
                cv.u.y = bf16pack(fa.z, fa.w);
                cv.u.z = bf16pack(fb.x, fb.y);
                cv.u.w = bf16pack(fb.z, fb.w);
                af[rt] = cv.v;
            }
        }
        bf16x8 bfr[8];
#pragma unroll
        for (int nt = 0; nt < 8; ++nt) {
            int n = nt * 16 + l16;
            bfr[nt] = *(const bf16x8*)&Ws[n * 128 + (((kb * 4 + quad) ^ l16) << 3)];
        }
#pragma unroll
        for (int rt = 0; rt < 2; ++rt)
#pragma unroll
            for (int nt = 0; nt < 8; ++nt)
                acc[rt][nt] = __builtin_amdgcn_mfma_f32_16x16x32_bf16(
                    af[rt], bfr[nt], acc[rt][nt], 0, 0, 0);
    }

    short* Ys = (short*)Y;
#pragma unroll
    for (int rt = 0; rt < 2; ++rt)
#pragma unroll
        for (int reg = 0; reg < 4; ++reg) {
            int row = rbase + rt * 16 + quad * 4 + reg;
            if (row < nrows) {
#pragma unroll
                for (int nt = 0; nt < 8; ++nt)
                    Ys[(size_t)row * 128 + nt * 16 + l16] = (short)f2bf(acc[rt][nt][reg]);
            }
        }
}

// ---------------- gather-aggregate: 2 nodes/wave, 16 gathers in flight ----
template <bool RELU>
__global__ __launch_bounds__(256) void aggregate(const unsigned int* __restrict__ Hb,
                                                 const int2* __restrict__ packed,
                                                 const int* __restrict__ row_ptr,
                                                 const float* __restrict__ dinv,
                                                 const float* __restrict__ bias,
                                                 unsigned int* __restrict__ Xb) {
    int v0 = blockIdx.x * 8 + (threadIdx.x >> 6) * 2;
    int v1 = v0 + 1;
    int lane = threadIdx.x & 63;
    if (v0 >= N_NODES) return;
    bool h1 = (v1 < N_NODES);

    int st0 = row_ptr[v0], en0 = row_ptr[v0 + 1];
    int st1 = h1 ? row_ptr[v1] : 0, en1 = h1 ? row_ptr[v1 + 1] : 0;
    float dv0 = dinv[v0], d20 = dv0 * dv0;
    float dv1 = h1 ? dinv[v1] : 0.f, d21 = dv1 * dv1;

    unsigned int su0 = Hb[(size_t)v0 * 64 + lane];
    float a0 = d20 * bflo(su0), a1 = d20 * bfhi(su0);
    unsigned int su1 = h1 ? Hb[(size_t)v1 * 64 + lane] : 0u;
    float b0 = d21 * bflo(su1), b1 = d21 * bfhi(su1);

    for (int c0 = st0, c1 = st1; c0 < en0 || c1 < en1; c0 += 32, c1 += 32) {
        int n0 = en0 - c0; n0 = n0 < 0 ? 0 : (n0 > 32 ? 32 : n0);
        int n1 = en1 - c1; n1 = n1 < 0 ? 0 : (n1 > 32 ? 32 : n1);
        int2 p = make_int2(0, 0);
        if (lane < 32) {
            if (lane < n0) p = packed[c0 + lane];
        } else {
            if (lane - 32 < n1) p = packed[c1 + lane - 32];
        }
        int nmax = n0 > n1 ? n0 : n1;
        for (int j = 0; j < nmax; j += 8) {
            int sA[8], sB[8];
            float nrA[8], nrB[8];
#pragma unroll
            for (int q = 0; q < 8; ++q) {
                sA[q] = __shfl(p.x, j + q);
                nrA[q] = __int_as_float(__shfl(p.y, j + q));
                sB[q] = __shfl(p.x, 32 + j + q);
                nrB[q] = __int_as_float(__shfl(p.y, 32 + j + q));
            }
            unsigned int uA[8], uB[8];
#pragma unroll
            for (int q = 0; q < 8; ++q) {
                uA[q] = Hb[(size_t)sA[q] * 64 + lane];
                uB[q] = Hb[(size_t)sB[q] * 64 + lane];
            }
#pragma unroll
            for (int q = 0; q < 8; ++q) {
                a0 = fmaf(nrA[q], bflo(uA[q]), a0);
                a1 = fmaf(nrA[q], bfhi(uA[q]), a1);
                b0 = fmaf(nrB[q], bflo(uB[q]), b0);
                b1 = fmaf(nrB[q], bfhi(uB[q]), b1);
            }
        }
    }

    if (RELU) {
        float2 bb = ((const float2*)bias)[lane];
        a0 = fmaxf(a0 + bb.x, 0.f);
        a1 = fmaxf(a1 + bb.y, 0.f);
        b0 = fmaxf(b0 + bb.x, 0.f);
        b1 = fmaxf(b1 + bb.y, 0.f);
    }
    Xb[(size_t)v0 * 64 + lane] = bf16pack(a0, a1);
    if (h1) Xb[(size_t)v1 * 64 + lane] = bf16pack(b0, b1);
}

// ---------------- edge scoring: 4 label edges per wave ----------------
__global__ __launch_bounds__(256) void score_kernel(const int* __restrict__ ea,
                                                    const int* __restrict__ eb,
                                                    const unsigned int* __restrict__ Xb,
                                                    const float* __restrict__ bias,
                                                    float* __restrict__ out) {
    int wbase = (blockIdx.x * 4 + (threadIdx.x >> 6)) * 4;
    int lane = threadIdx.x & 63;
    if (wbase >= N_LABEL) return;
    int ne = N_LABEL - wbase;
    if (ne > 4) ne = 4;
    float2 bb = ((const float2*)bias)[lane];

    unsigned int ua[4], ub[4];
#pragma unroll
    for (int e = 0; e < 4; ++e)
        if (e < ne) {
            int ia = ea[wbase + e], ib = eb[wbase + e];
            ua[e] = Xb[(size_t)ia * 64 + lane];
            ub[e] = Xb[(size_t)ib * 64 + lane];
        }
#pragma unroll
    for (int e = 0; e < 4; ++e)
        if (e < ne) {
            float p = (bflo(ua[e]) + bb.x) * (bflo(ub[e]) + bb.x) +
                      (bfhi(ua[e]) + bb.y) * (bfhi(ub[e]) + bb.y);
#pragma unroll
            for (int off = 32; off > 0; off >>= 1) p += __shfl_down(p, off);
            if (lane == 0) out[wbase + e] = p;
        }
}

extern "C" void kernel_launch(void* const* d_in, const int* in_sizes, int n_in,
                              void* d_out, int out_size, void* d_ws, size_t ws_size,
                              hipStream_t stream) {
    const float* feat = (const float*)d_in[0];
    const int* ei = (const int*)d_in[1];
    const int* eli = (const int*)d_in[2];
    const float* W1 = (const float*)d_in[3];
    const float* b1 = (const float*)d_in[4];
    const float* W2 = (const float*)d_in[5];
    const float* b2 = (const float*)d_in[6];
    float* out = (float*)d_out;

    const int* src = ei;
    const int* dst = ei + N_EDGES;
    const int* la = eli;
    const int* lb = eli + N_LABEL;

    int* counts = (int*)d_ws;                        // N ints
    int* row_ptr = counts + N_NODES;                 // N+4 ints
    int* bsums = row_ptr + N_NODES + 4;              // 128
    float* dinv = (float*)(bsums + 128);             // N
    unsigned short* wt1 = (unsigned short*)(dinv + N_NODES);  // 16384 ushort
    unsigned short* wt2 = wt1 + 16384;                        // 16384 ushort
    int2* packed = (int2*)(wt2 + 16384);                      // E int2 (8 MB)
    unsigned int* Hb = (unsigned int*)(packed + N_EDGES);     // N*64 uints
    unsigned int* Xb = Hb + (size_t)N_NODES * 64;             // N*64 uints

    const int TB = 256;
    int gScan = (N_NODES + 1023) / 1024;     // 98
    int gGemm = (N_NODES + BM - 1) / BM;     // 782
    int gAgg = (N_NODES + 7) / 8;            // 12500
    int gScore = (N_LABEL + 15) / 16;        // 12500

    hipMemsetAsync(counts, 0, N_NODES * sizeof(int), stream);

    // CSR build (+ W conversion folded into first launch)
    deg_hist_w2bf<<<G_EDGE + 128, TB, 0, stream>>>(dst, counts, W1, W2, wt1, wt2);
    scan_reduce<<<gScan, TB, 0, stream>>>(counts, bsums, dinv);
    scan_apply<<<gScan, TB, 0, stream>>>(counts, bsums, row_ptr);
    fill_csr<<<G_EDGE, TB, 0, stream>>>(src, dst, dinv, row_ptr, counts, packed);

    // layer 1
    gemm128_mfma<false><<<gGemm, TB, 0, stream>>>(feat, wt1, Hb, N_NODES);
    aggregate<true><<<gAgg, TB, 0, stream>>>(Hb, packed, row_ptr, dinv, b1, Xb);

    // layer 2
    gemm128_mfma<true><<<gGemm, TB, 0, stream>>>(Xb, wt2, Hb, N_NODES);
    aggregate<false><<<gAgg, TB, 0, stream>>>(Hb, packed, row_ptr, dinv, b2, Xb);

    // scoring (b2 folded in)
    score_kernel<<<gScore, TB, 0, stream>>>(la, lb, Xb, b2, out);
}